// Round 2
// baseline (723.423 us; speedup 1.0000x reference)
//
#include <hip/hip_runtime.h>
#include <hip/hip_bf16.h>
#include <math.h>

#define NEG_INF (-1e9f)
#define B_   16
#define C_   192
#define TX   384
#define TY   1536
#define NW   (TY / 64)   // 24 decision words per x

#define BM 64
#define BN 64
#define BK 16

// ---------------------------------------------------------------------------
// K1: per-(b,t) row constants r = logp1 + logp4
// ---------------------------------------------------------------------------
__global__ __launch_bounds__(128) void k_rowconst(const float* __restrict__ m_p,
                                                  const float* __restrict__ logs_p,
                                                  float* __restrict__ r) {
    const int b = blockIdx.y;
    const int t = blockIdx.x * 128 + threadIdx.x;
    const float* mp = m_p + b * C_ * TX + t;
    const float* lp = logs_p + b * C_ * TX + t;
    const float c0 = -0.9189385332046727f;  // -0.5*log(2*pi)
    float s = 0.0f;
    for (int c = 0; c < C_; ++c) {
        float ls = lp[c * TX];
        float m  = mp[c * TX];
        float os = expf(-2.0f * ls);
        s += (c0 - ls) - 0.5f * m * m * os;
    }
    r[b * TX + t] = s;
}

// ---------------------------------------------------------------------------
// K2: logp^T[b,s,t] = r[b,t] + sum_c( os[c,t]*(-0.5 z[c,s]^2) + (m os)[c,t]*z[c,s] )
// TRANSPOSED output [B,Ty,Tx] so the DP kernel reads contiguous rows.
// fp32 tiled GEMM, 64x64 tile, BK=16, 256 threads, 4x4 accum/thread.
// Accumulation order per (t,s) identical to round-1 kernel -> bit-identical logp.
// ---------------------------------------------------------------------------
__global__ __launch_bounds__(256) void k_logp(const float* __restrict__ z_p,
                                              const float* __restrict__ m_p,
                                              const float* __restrict__ logs_p,
                                              const float* __restrict__ r,
                                              float* __restrict__ outT) {
    __shared__ float Zs1[BK][BM];   // -0.5 z^2   (M-side = s/Ty)
    __shared__ float Zs2[BK][BM];   // z
    __shared__ float Ms1[BK][BN];   // os         (N-side = t/Tx)
    __shared__ float Ms2[BK][BN];   // m*os

    const int b   = blockIdx.z;
    const int tn0 = blockIdx.x * BN;   // t (Tx)
    const int sm0 = blockIdx.y * BM;   // s (Ty)
    const int tid = threadIdx.x;
    const int lrow = tid >> 4;            // 0..15 (k row for staging)
    const int lcol = (tid & 15) << 2;     // 0,4,...,60
    const int tx_ = tid & 15;             // n quadrant (t)
    const int ty_ = tid >> 4;             // m quadrant (s)

    const float* mb = m_p + b * C_ * TX;
    const float* lb = logs_p + b * C_ * TX;
    const float* zb = z_p + b * C_ * TY;

    float acc[4][4] = {};

    for (int kk = 0; kk < C_; kk += BK) {
        float4 m4 = *(const float4*)(mb + (kk + lrow) * TX + tn0 + lcol);
        float4 l4 = *(const float4*)(lb + (kk + lrow) * TX + tn0 + lcol);
        float4 z4 = *(const float4*)(zb + (kk + lrow) * TY + sm0 + lcol);

        const float mm[4] = {m4.x, m4.y, m4.z, m4.w};
        const float ll[4] = {l4.x, l4.y, l4.z, l4.w};
        const float zz[4] = {z4.x, z4.y, z4.z, z4.w};
        float osv[4], a2v[4], u1v[4], u2v[4];
#pragma unroll
        for (int i = 0; i < 4; ++i) {
            float os = expf(-2.0f * ll[i]);
            osv[i] = os;
            a2v[i] = mm[i] * os;
            u1v[i] = -0.5f * zz[i] * zz[i];
            u2v[i] = zz[i];
        }

        __syncthreads();   // protect previous iteration's LDS reads
#pragma unroll
        for (int i = 0; i < 4; ++i) {
            Ms1[lrow][lcol + i] = osv[i];
            Ms2[lrow][lcol + i] = a2v[i];
            Zs1[lrow][lcol + i] = u1v[i];
            Zs2[lrow][lcol + i] = u2v[i];
        }
        __syncthreads();

#pragma unroll
        for (int k = 0; k < BK; ++k) {
            float4 z1 = *(const float4*)&Zs1[k][ty_ * 4];   // u1 (s)
            float4 z2 = *(const float4*)&Zs2[k][ty_ * 4];   // u2 (s)
            float4 m1 = *(const float4*)&Ms1[k][tx_ * 4];   // a1 (t)
            float4 m2 = *(const float4*)&Ms2[k][tx_ * 4];   // a2 (t)
            const float u1a[4] = {z1.x, z1.y, z1.z, z1.w};
            const float u2a[4] = {z2.x, z2.y, z2.z, z2.w};
            const float a1a[4] = {m1.x, m1.y, m1.z, m1.w};
            const float a2a[4] = {m2.x, m2.y, m2.z, m2.w};
#pragma unroll
            for (int i = 0; i < 4; ++i)      // s frag
#pragma unroll
                for (int j = 0; j < 4; ++j)  // t frag
                    acc[i][j] = fmaf(a1a[j], u1a[i], fmaf(a2a[j], u2a[i], acc[i][j]));
        }
    }

    float4 r4 = *(const float4*)(r + b * TX + tn0 + tx_ * 4);
    const float rr[4] = {r4.x, r4.y, r4.z, r4.w};
#pragma unroll
    for (int i = 0; i < 4; ++i) {
        const int srow = sm0 + ty_ * 4 + i;
        float4 o;
        o.x = acc[i][0] + rr[0];
        o.y = acc[i][1] + rr[1];
        o.z = acc[i][2] + rr[2];
        o.w = acc[i][3] + rr[3];
        *(float4*)(outT + ((size_t)(b * TY + srow)) * TX + tn0 + tx_ * 4) = o;
    }
}

// ---------------------------------------------------------------------------
// K3: monotonic alignment search. ONE WAVE (64 threads) per batch, 6 DP cells
// per lane, zero barriers in the main loop. Decision bits accumulated in
// registers and flushed to LDS in [x][y/64] layout for a cached backtrack.
// ---------------------------------------------------------------------------
__global__ __launch_bounds__(64) void k_dp(const float* __restrict__ logpT,
                                           const float* __restrict__ x_mask,
                                           const float* __restrict__ y_mask,
                                           int* __restrict__ idx_out) {
    extern __shared__ unsigned long long decw[];   // [TX][NW]

    const int b = blockIdx.x;
    const int l = threadIdx.x;
    const int x0 = 6 * l;

    // ---- lengths via ballot+popcount (order-independent) ----
    int tx = 0, ty = 0;
#pragma unroll
    for (int i = 0; i < TX / 64; ++i)
        tx += __popcll(__ballot(x_mask[b * TX + i * 64 + l] > 0.5f));
#pragma unroll
    for (int i = 0; i < TY / 64; ++i)
        ty += __popcll(__ballot(y_mask[b * TY + i * 64 + l] > 0.5f));
    const unsigned ud = (unsigned)(ty - tx);   // feasible band width (>=0)

    const float* rp = logpT + (size_t)b * TY * TX + x0;

    float v[6];
    unsigned long long w[6];
#pragma unroll
    for (int k = 0; k < 6; ++k) { v[k] = NEG_INF; w[k] = 0ULL; }

    float cA[6], cB[6], cC[6];
    auto loadc = [&](float* c, int y) {
        const float2* p = (const float2*)(rp + (size_t)y * TX);
        float2 a = p[0], d2 = p[1], e2 = p[2];
        c[0] = a.x; c[1] = a.y; c[2] = d2.x; c[3] = d2.y; c[4] = e2.x; c[5] = e2.y;
    };

    auto step = [&](int y, const float* c) {
        float vp5 = __shfl_up(v[5], 1);          // neighbor lane's old v[5]
        const unsigned long long bit = 1ULL << (y & 63);
#pragma unroll
        for (int k = 5; k >= 1; --k) {           // descending: v[k-1] still old
            float vold = v[k];
            float vm   = v[k - 1];
            bool diag  = (x0 + k == y);
            bool dec   = diag || (vold < vm);    // x>0 always for k>=1
            if (dec) w[k] |= bit;
            float vs = diag ? NEG_INF : vold;
            float nv = fmaxf(vs, vm) + c[k];
            v[k] = ((unsigned)(y - (x0 + k)) <= ud) ? nv : NEG_INF;
        }
        {   // k = 0
            float vold = v[0];
            float vm   = (l == 0) ? ((y == 0) ? 0.0f : NEG_INF) : vp5;
            bool diag  = (x0 == y);
            bool dec   = (l != 0) && (diag || (vold < vm));
            if (dec) w[0] |= bit;
            float vs = diag ? NEG_INF : vold;
            float nv = fmaxf(vs, vm) + c[0];
            v[0] = ((unsigned)(y - x0) <= ud) ? nv : NEG_INF;
        }
        if ((y & 63) == 63) {                    // flush decision words
#pragma unroll
            for (int k = 0; k < 6; ++k) {
                decw[(x0 + k) * NW + (y >> 6)] = w[k];
                w[k] = 0ULL;
            }
        }
    };

    loadc(cA, 0); loadc(cB, 1); loadc(cC, 2);
    for (int y = 0; y < TY; y += 3) {
        step(y, cA);     if (y + 3 < TY) loadc(cA, y + 3);
        step(y + 1, cB); if (y + 4 < TY) loadc(cB, y + 4);
        step(y + 2, cC); if (y + 5 < TY) loadc(cC, y + 5);
    }

    __syncthreads();

    // ---- backtrack: serial bit-chase with word caching + x-1 prefetch ----
    if (l == 0) {
        int idx = tx - 1;
        int* io = idx_out + b * TY;
        int blk = (TY - 1) >> 6;
        unsigned long long wcur = decw[idx * NW + blk];
        unsigned long long wnxt = (idx > 0) ? decw[(idx - 1) * NW + blk] : 0ULL;
        for (int y = TY - 1; y >= 0; --y) {
            const int nb = y >> 6;
            if (nb != blk) {
                blk = nb;
                wcur = decw[idx * NW + blk];
                wnxt = (idx > 0) ? decw[(idx - 1) * NW + blk] : 0ULL;
            }
            const bool active = y < ty;
            io[y] = active ? idx : -1;
            if (active && ((wcur >> (y & 63)) & 1ULL)) {
                --idx;
                wcur = wnxt;
                wnxt = (idx > 0) ? decw[(idx - 1) * NW + blk] : 0ULL;
            }
        }
    }
}

// ---------------------------------------------------------------------------
// K4: write the one-hot path. Fully overwrites d_out (which held logp^T).
// ---------------------------------------------------------------------------
__global__ __launch_bounds__(384) void k_path(const int* __restrict__ idx_arr,
                                              float* __restrict__ out) {
    const int b = blockIdx.y;
    const int x = blockIdx.x;
    const int t = threadIdx.x;       // one float4 per thread along y
    const int y0 = t * 4;
    int4 iv = *(const int4*)(idx_arr + b * TY + y0);
    float4 o;
    o.x = (iv.x == x) ? 1.0f : 0.0f;
    o.y = (iv.y == x) ? 1.0f : 0.0f;
    o.z = (iv.z == x) ? 1.0f : 0.0f;
    o.w = (iv.w == x) ? 1.0f : 0.0f;
    *(float4*)(out + ((size_t)(b * TX + x)) * TY + y0) = o;
}

// ---------------------------------------------------------------------------
extern "C" void kernel_launch(void* const* d_in, const int* in_sizes, int n_in,
                              void* d_out, int out_size, void* d_ws, size_t ws_size,
                              hipStream_t stream) {
    const float* z_p    = (const float*)d_in[0];
    const float* m_p    = (const float*)d_in[1];
    const float* logs_p = (const float*)d_in[2];
    const float* x_mask = (const float*)d_in[3];
    const float* y_mask = (const float*)d_in[4];
    float* out = (float*)d_out;

    float* r       = (float*)d_ws;                           // B*TX floats
    int*   idx_arr = (int*)((char*)d_ws + B_ * TX * 4);      // B*TY ints

    // K3 dynamic LDS: 384 * 24 * 8 = 73728 B (> 64KB default cap)
    static const size_t dp_smem = (size_t)TX * NW * 8;
    (void)hipFuncSetAttribute((const void*)k_dp,
                              hipFuncAttributeMaxDynamicSharedMemorySize,
                              (int)dp_smem);

    k_rowconst<<<dim3(TX / 128, B_), 128, 0, stream>>>(m_p, logs_p, r);
    k_logp<<<dim3(TX / BN, TY / BM, B_), 256, 0, stream>>>(z_p, m_p, logs_p, r, out);
    k_dp<<<B_, 64, dp_smem, stream>>>(out, x_mask, y_mask, idx_arr);
    k_path<<<dim3(TX, B_), TX, 0, stream>>>(idx_arr, out);
}

// Round 3
// 519.159 us; speedup vs baseline: 1.3934x; 1.3934x over previous
//
#include <hip/hip_runtime.h>
#include <hip/hip_bf16.h>
#include <math.h>

#define NEG_INF (-1e9f)
#define B_   16
#define C_   192
#define TX   384
#define TY   1536
#define NB32 (TY / 32)    // 48 decision words per x (32-bit)
#define NWP  49           // padded stride (bank-conflict fix)

#define BM 64
#define BN 64
#define BK 16

// ---------------------------------------------------------------------------
// K1: per-(b,t) row constants r = logp1 + logp4
// ---------------------------------------------------------------------------
__global__ __launch_bounds__(128) void k_rowconst(const float* __restrict__ m_p,
                                                  const float* __restrict__ logs_p,
                                                  float* __restrict__ r) {
    const int b = blockIdx.y;
    const int t = blockIdx.x * 128 + threadIdx.x;
    const float* mp = m_p + b * C_ * TX + t;
    const float* lp = logs_p + b * C_ * TX + t;
    const float c0 = -0.9189385332046727f;  // -0.5*log(2*pi)
    float s = 0.0f;
    for (int c = 0; c < C_; ++c) {
        float ls = lp[c * TX];
        float m  = mp[c * TX];
        float os = expf(-2.0f * ls);
        s += (c0 - ls) - 0.5f * m * m * os;
    }
    r[b * TX + t] = s;
}

// ---------------------------------------------------------------------------
// K2: logp^T[b,s,t] (TRANSPOSED, [B,Ty,Tx]) so the DP reads contiguous rows.
// fp32 tiled GEMM, 64x64 tile, BK=16, 256 threads, 4x4 accum/thread.
// Per-element fp32 accumulation order identical to previous rounds.
// ---------------------------------------------------------------------------
__global__ __launch_bounds__(256) void k_logp(const float* __restrict__ z_p,
                                              const float* __restrict__ m_p,
                                              const float* __restrict__ logs_p,
                                              const float* __restrict__ r,
                                              float* __restrict__ outT) {
    __shared__ float Zs1[BK][BM];   // -0.5 z^2   (M-side = s/Ty)
    __shared__ float Zs2[BK][BM];   // z
    __shared__ float Ms1[BK][BN];   // os         (N-side = t/Tx)
    __shared__ float Ms2[BK][BN];   // m*os

    const int b   = blockIdx.z;
    const int tn0 = blockIdx.x * BN;   // t (Tx)
    const int sm0 = blockIdx.y * BM;   // s (Ty)
    const int tid = threadIdx.x;
    const int lrow = tid >> 4;
    const int lcol = (tid & 15) << 2;
    const int tx_ = tid & 15;          // t quadrant
    const int ty_ = tid >> 4;          // s quadrant

    const float* mb = m_p + b * C_ * TX;
    const float* lb = logs_p + b * C_ * TX;
    const float* zb = z_p + b * C_ * TY;

    float acc[4][4] = {};

    for (int kk = 0; kk < C_; kk += BK) {
        float4 m4 = *(const float4*)(mb + (kk + lrow) * TX + tn0 + lcol);
        float4 l4 = *(const float4*)(lb + (kk + lrow) * TX + tn0 + lcol);
        float4 z4 = *(const float4*)(zb + (kk + lrow) * TY + sm0 + lcol);

        const float mm[4] = {m4.x, m4.y, m4.z, m4.w};
        const float ll[4] = {l4.x, l4.y, l4.z, l4.w};
        const float zz[4] = {z4.x, z4.y, z4.z, z4.w};
        float osv[4], a2v[4], u1v[4], u2v[4];
#pragma unroll
        for (int i = 0; i < 4; ++i) {
            float os = expf(-2.0f * ll[i]);
            osv[i] = os;
            a2v[i] = mm[i] * os;
            u1v[i] = -0.5f * zz[i] * zz[i];
            u2v[i] = zz[i];
        }

        __syncthreads();
#pragma unroll
        for (int i = 0; i < 4; ++i) {
            Ms1[lrow][lcol + i] = osv[i];
            Ms2[lrow][lcol + i] = a2v[i];
            Zs1[lrow][lcol + i] = u1v[i];
            Zs2[lrow][lcol + i] = u2v[i];
        }
        __syncthreads();

#pragma unroll
        for (int k = 0; k < BK; ++k) {
            float4 z1 = *(const float4*)&Zs1[k][ty_ * 4];
            float4 z2 = *(const float4*)&Zs2[k][ty_ * 4];
            float4 m1 = *(const float4*)&Ms1[k][tx_ * 4];
            float4 m2 = *(const float4*)&Ms2[k][tx_ * 4];
            const float u1a[4] = {z1.x, z1.y, z1.z, z1.w};
            const float u2a[4] = {z2.x, z2.y, z2.z, z2.w};
            const float a1a[4] = {m1.x, m1.y, m1.z, m1.w};
            const float a2a[4] = {m2.x, m2.y, m2.z, m2.w};
#pragma unroll
            for (int i = 0; i < 4; ++i)
#pragma unroll
                for (int j = 0; j < 4; ++j)
                    acc[i][j] = fmaf(a1a[j], u1a[i], fmaf(a2a[j], u2a[i], acc[i][j]));
        }
    }

    float4 r4 = *(const float4*)(r + b * TX + tn0 + tx_ * 4);
    const float rr[4] = {r4.x, r4.y, r4.z, r4.w};
#pragma unroll
    for (int i = 0; i < 4; ++i) {
        const int srow = sm0 + ty_ * 4 + i;
        float4 o;
        o.x = acc[i][0] + rr[0];
        o.y = acc[i][1] + rr[1];
        o.z = acc[i][2] + rr[2];
        o.w = acc[i][3] + rr[3];
        *(float4*)(outT + ((size_t)(b * TY + srow)) * TX + tn0 + tx_ * 4) = o;
    }
}

// ---------------------------------------------------------------------------
// K3: MAS DP. One wave per batch, 6 cells/lane, zero barriers, 8-deep row
// prefetch, lean 8-VALU-per-cell step (diag & x==0 cases folded into the
// feasibility-masked values), 32-bit shift-in decision words.
// ---------------------------------------------------------------------------
__global__ __launch_bounds__(64) void k_dp(const float* __restrict__ logpT,
                                           const float* __restrict__ x_mask,
                                           const float* __restrict__ y_mask,
                                           int* __restrict__ idx_out) {
    extern __shared__ unsigned decw[];   // [TX][NWP]

    const int b = blockIdx.x;
    const int l = threadIdx.x;
    const int x0 = 6 * l;

    // ---- lengths via ballot+popcount ----
    int tx = 0, ty = 0;
#pragma unroll
    for (int i = 0; i < TX / 64; ++i)
        tx += __popcll(__ballot(x_mask[b * TX + i * 64 + l] > 0.5f));
#pragma unroll
    for (int i = 0; i < TY / 64; ++i)
        ty += __popcll(__ballot(y_mask[b * TY + i * 64 + l] > 0.5f));
    const unsigned ud = (unsigned)(ty - tx);   // band width (>=0)

    const float* rp = logpT + (size_t)b * TY * TX + x0;

    float v[6];
#pragma unroll
    for (int k = 0; k < 6; ++k) v[k] = NEG_INF;
    unsigned w[6] = {0u, 0u, 0u, 0u, 0u, 0u};

    float R[8][6];
    auto loadrow = [&](float* c, int y) {
        const float2* p = (const float2*)(rp + (size_t)y * TX);
        float2 a = p[0], d2 = p[1], e2 = p[2];
        c[0] = a.x; c[1] = a.y; c[2] = d2.x; c[3] = d2.y; c[4] = e2.x; c[5] = e2.y;
    };
#pragma unroll
    for (int u = 0; u < 8; ++u) loadrow(R[u], u);

    for (int blk = 0; blk < NB32; ++blk) {
        for (int j = 0; j < 4; ++j) {
            const int y0 = blk * 32 + j * 8;
#pragma unroll
            for (int u = 0; u < 8; ++u) {
                const int y = y0 + u;
                float vp5 = __shfl_up(v[5], 1);
#pragma unroll
                for (int k = 5; k >= 1; --k) {
                    float vold = v[k];
                    float vm   = v[k - 1];
                    w[k] = (w[k] << 1) | (vold < vm ? 1u : 0u);
                    float nv = fmaxf(vold, vm) + R[u][k];
                    v[k] = ((unsigned)(y - (x0 + k)) <= ud) ? nv : NEG_INF;
                }
                {
                    float vold = v[0];
                    float vm   = (l == 0) ? ((y == 0) ? 0.0f : NEG_INF) : vp5;
                    w[0] = (w[0] << 1) | (vold < vm ? 1u : 0u);
                    float nv = fmaxf(vold, vm) + R[u][0];
                    v[0] = ((unsigned)(y - x0) <= ud) ? nv : NEG_INF;
                }
                if (y + 8 < TY) loadrow(R[u], y + 8);
            }
        }
#pragma unroll
        for (int k = 0; k < 6; ++k) {
            decw[(x0 + k) * NWP + blk] = w[k];
            w[k] = 0u;
        }
    }

    __syncthreads();

    // ---- backtrack: serial bit-chase, 3-deep speculative word prefetch ----
    if (l == 0) {
        int idx = tx - 1;
        int* io = idx_out + b * TY;
        int blk = NB32 - 1;
        auto W = [&](int i, int bb) -> unsigned {
            return (i >= 0) ? decw[i * NWP + bb] : 0u;
        };
        unsigned w0 = W(idx, blk), w1 = W(idx - 1, blk),
                 w2 = W(idx - 2, blk), w3 = W(idx - 3, blk);
        for (int y = TY - 1; y >= 0; --y) {
            const int nb = y >> 5;
            if (nb != blk) {
                blk = nb;
                w0 = W(idx, blk); w1 = W(idx - 1, blk);
                w2 = W(idx - 2, blk); w3 = W(idx - 3, blk);
            }
            const bool active = y < ty;
            io[y] = active ? idx : -1;
            if (active && ((w0 >> (31 - (y & 31))) & 1u)) {
                --idx;
                w0 = w1; w1 = w2; w2 = w3; w3 = W(idx - 3, blk);
            }
        }
    }
}

// ---------------------------------------------------------------------------
// K4: write the one-hot path. Fully overwrites d_out (which held logp^T).
// ---------------------------------------------------------------------------
__global__ __launch_bounds__(384) void k_path(const int* __restrict__ idx_arr,
                                              float* __restrict__ out) {
    const int b = blockIdx.y;
    const int x = blockIdx.x;
    const int t = threadIdx.x;
    const int y0 = t * 4;
    int4 iv = *(const int4*)(idx_arr + b * TY + y0);
    float4 o;
    o.x = (iv.x == x) ? 1.0f : 0.0f;
    o.y = (iv.y == x) ? 1.0f : 0.0f;
    o.z = (iv.z == x) ? 1.0f : 0.0f;
    o.w = (iv.w == x) ? 1.0f : 0.0f;
    *(float4*)(out + ((size_t)(b * TX + x)) * TY + y0) = o;
}

// ---------------------------------------------------------------------------
extern "C" void kernel_launch(void* const* d_in, const int* in_sizes, int n_in,
                              void* d_out, int out_size, void* d_ws, size_t ws_size,
                              hipStream_t stream) {
    const float* z_p    = (const float*)d_in[0];
    const float* m_p    = (const float*)d_in[1];
    const float* logs_p = (const float*)d_in[2];
    const float* x_mask = (const float*)d_in[3];
    const float* y_mask = (const float*)d_in[4];
    float* out = (float*)d_out;

    float* r       = (float*)d_ws;                           // B*TX floats
    int*   idx_arr = (int*)((char*)d_ws + B_ * TX * 4);      // B*TY ints

    // K3 dynamic LDS: 384 * 49 * 4 = 75264 B (> 64KB default cap)
    static const size_t dp_smem = (size_t)TX * NWP * 4;
    (void)hipFuncSetAttribute((const void*)k_dp,
                              hipFuncAttributeMaxDynamicSharedMemorySize,
                              (int)dp_smem);

    k_rowconst<<<dim3(TX / 128, B_), 128, 0, stream>>>(m_p, logs_p, r);
    k_logp<<<dim3(TX / BN, TY / BM, B_), 256, 0, stream>>>(z_p, m_p, logs_p, r, out);
    k_dp<<<B_, 64, dp_smem, stream>>>(out, x_mask, y_mask, idx_arr);
    k_path<<<dim3(TX, B_), TX, 0, stream>>>(idx_arr, out);
}